// Round 3
// baseline (1488.132 us; speedup 1.0000x reference)
//
#include <hip/hip_runtime.h>
#include <hip/hip_bf16.h>

#define NB 8
#define NL 4096
#define ND 768
#define NE 8
#define NK 2
#define NH 1536
#define NTOK (NB*NL)        // 32768
#define NPAIR (NTOK*NK)     // 65536
#define BM 128
#define BN 128
#define BK 64
#define ROWTILES 520        // ceil((NPAIR + NE*(BM-1))/BM)
#define PADN (ROWTILES*BM)  // 66560

typedef __attribute__((ext_vector_type(8))) short bf16x8;
typedef __attribute__((ext_vector_type(4))) float f32x4;

static __device__ __forceinline__ unsigned short f2bf(float f) {
    union { float f; unsigned int u; } v; v.f = f;
    unsigned int r = v.u + 0x7fffu + ((v.u >> 16) & 1u);
    return (unsigned short)(r >> 16);
}

// ---------------- routing ----------------
__global__ void router_kernel(const float* __restrict__ scores,
                              int* __restrict__ counts,
                              int* __restrict__ te, float* __restrict__ tw) {
    int t = blockIdx.x * 256 + threadIdx.x;
    if (t >= NTOK) return;
    float s[NE];
#pragma unroll
    for (int e = 0; e < NE; ++e) s[e] = scores[t * NE + e];
    int i0 = 0; float m0 = s[0];
#pragma unroll
    for (int e = 1; e < NE; ++e) if (s[e] > m0) { m0 = s[e]; i0 = e; }
    int i1 = -1; float m1 = -1e30f;
#pragma unroll
    for (int e = 0; e < NE; ++e) if (e != i0 && s[e] > m1) { m1 = s[e]; i1 = e; }
    float z = expf(m1 - m0);            // <= 1
    float inv = 1.f / (1.f + z);
    te[t * 2 + 0] = i0; te[t * 2 + 1] = i1;
    tw[t * 2 + 0] = inv; tw[t * 2 + 1] = z * inv;
    atomicAdd(&counts[i0], 1);
    atomicAdd(&counts[i1], 1);
}

__global__ void scan_kernel(const int* __restrict__ counts,
                            int* __restrict__ offsets, int* __restrict__ cursors) {
    if (threadIdx.x == 0) {
        int off = 0;
        for (int e = 0; e < NE; ++e) {
            offsets[e] = off;
            cursors[e] = off;
            off += ((counts[e] + BM - 1) / BM) * BM;   // 128-aligned segments
        }
        offsets[NE] = off;
    }
}

__global__ void fill_kernel(const int* __restrict__ te, const float* __restrict__ tw,
                            int* __restrict__ cursors,
                            int* __restrict__ ptok, float* __restrict__ pw) {
    int t = blockIdx.x * 256 + threadIdx.x;
    if (t >= NTOK) return;
#pragma unroll
    for (int k = 0; k < NK; ++k) {
        int e = te[t * 2 + k];
        int pos = atomicAdd(&cursors[e], 1);
        ptok[pos] = t;
        pw[pos] = tw[t * 2 + k];
    }
}

// ---------------- operand pre-conversion ----------------
// fp32 [n8*8] -> bf16, 8 elems/thread
__global__ void cvt_kernel(const float* __restrict__ src, unsigned short* __restrict__ dst, int n8) {
    int i = blockIdx.x * 256 + threadIdx.x;
    if (i >= n8) return;
    const float4* p = (const float4*)(src + (size_t)i * 8);
    float4 a = p[0], b = p[1];
    uint4 v;
    v.x = f2bf(a.x) | ((unsigned)f2bf(a.y) << 16);
    v.y = f2bf(a.z) | ((unsigned)f2bf(a.w) << 16);
    v.z = f2bf(b.x) | ((unsigned)f2bf(b.y) << 16);
    v.w = f2bf(b.z) | ((unsigned)f2bf(b.w) << 16);
    *(uint4*)(dst + (size_t)i * 8) = v;
}

// per-expert transpose+convert: src [E][R][C] fp32 -> dst [E][C][R] bf16
__global__ void tcvt_kernel(const float* __restrict__ src, unsigned short* __restrict__ dst,
                            int R, int C) {
    __shared__ float t[32][33];
    int e = blockIdx.z;
    const float* s = src + (size_t)e * R * C;
    unsigned short* d = dst + (size_t)e * R * C;
    int c0 = blockIdx.x * 32, r0 = blockIdx.y * 32;
    int tx = threadIdx.x & 31, ty4 = (threadIdx.x >> 5) * 4;
#pragma unroll
    for (int i = 0; i < 4; ++i)
        t[ty4 + i][tx] = s[(size_t)(r0 + ty4 + i) * C + c0 + tx];
    __syncthreads();
#pragma unroll
    for (int i = 0; i < 4; ++i)
        d[(size_t)(c0 + ty4 + i) * R + r0 + tx] = f2bf(t[tx][ty4 + i]);
}

// ---------------- GEMM1: h = (X@W1) * sigmoid(X@Wg) * w  (bf16 out, full H) ----------------
template<bool PRE>
__global__ __launch_bounds__(256, 2) void gemm1_kernel(
    const float* __restrict__ hidden, const unsigned short* __restrict__ hidbf,
    const float* __restrict__ W1, const float* __restrict__ Wg,
    const unsigned short* __restrict__ W1t, const unsigned short* __restrict__ Wgt,
    const int* __restrict__ offsets, const int* __restrict__ ptok,
    const float* __restrict__ pw, unsigned short* __restrict__ hbuf, int tile0)
{
    __shared__ unsigned short lA[BM * BK];
    __shared__ unsigned short lB1[BN * BK];
    __shared__ unsigned short lBg[BN * BK];

    const int tid = threadIdx.x;
    const int lane = tid & 63;
    const int wid = tid >> 6;
    const int wr = wid >> 1, wc = wid & 1;
    const int row0 = (tile0 + blockIdx.x) * BM;   // global pair-row base
    const int rowbase = tile0 * BM;               // hbuf local base
    const int col0 = blockIdx.y * BN;             // H column base

    int e = 0;
#pragma unroll
    for (int i = 1; i < NE; ++i) e += (row0 >= offsets[i]) ? 1 : 0;

    const int sr = tid >> 1;               // staging row (A) / col (B): 0..127
    const int sck = (tid & 1) * 4;         // 16B-chunk base: 0 or 4
    const int stok = ptok[row0 + sr];
    const int gcolB = col0 + sr;           // H column this thread stages

    const size_t wbase = (size_t)e * ND * NH;

    f32x4 acc1[4][4], accg[4][4];
#pragma unroll
    for (int m = 0; m < 4; ++m)
#pragma unroll
        for (int n = 0; n < 4; ++n) {
            acc1[m][n] = (f32x4){0.f, 0.f, 0.f, 0.f};
            accg[m][n] = (f32x4){0.f, 0.f, 0.f, 0.f};
        }

    for (int k0 = 0; k0 < ND; k0 += BK) {
        // ---- stage A (gather rows of X) ----
#pragma unroll
        for (int i = 0; i < 4; ++i) {
            int ck = sck + i;
            uint4 v;
            if (stok >= 0) {
                if (PRE) {
                    v = *(const uint4*)(hidbf + (size_t)stok * ND + k0 + ck * 8);
                } else {
                    const float4* p = (const float4*)(hidden + (size_t)stok * ND + k0 + ck * 8);
                    float4 f0 = p[0], f1 = p[1];
                    v.x = f2bf(f0.x) | ((unsigned)f2bf(f0.y) << 16);
                    v.y = f2bf(f0.z) | ((unsigned)f2bf(f0.w) << 16);
                    v.z = f2bf(f1.x) | ((unsigned)f2bf(f1.y) << 16);
                    v.w = f2bf(f1.z) | ((unsigned)f2bf(f1.w) << 16);
                }
            } else {
                v = make_uint4(0u, 0u, 0u, 0u);
            }
            *(uint4*)&lA[sr * BK + ((ck ^ (sr & 7)) * 8)] = v;
        }
        // ---- stage B1 / Bg ----
#pragma unroll
        for (int i = 0; i < 4; ++i) {
            int ck = sck + i;
            uint4 v1, vg;
            if (PRE) {
                v1 = *(const uint4*)(W1t + wbase + (size_t)gcolB * ND + k0 + ck * 8);
                vg = *(const uint4*)(Wgt + wbase + (size_t)gcolB * ND + k0 + ck * 8);
            } else {
                const float* bp1 = W1 + wbase + (size_t)(k0 + ck * 8) * NH + gcolB;
                const float* bpg = Wg + wbase + (size_t)(k0 + ck * 8) * NH + gcolB;
                v1.x = f2bf(bp1[0 * NH]) | ((unsigned)f2bf(bp1[1 * NH]) << 16);
                v1.y = f2bf(bp1[2 * NH]) | ((unsigned)f2bf(bp1[3 * NH]) << 16);
                v1.z = f2bf(bp1[4 * NH]) | ((unsigned)f2bf(bp1[5 * NH]) << 16);
                v1.w = f2bf(bp1[6 * NH]) | ((unsigned)f2bf(bp1[7 * NH]) << 16);
                vg.x = f2bf(bpg[0 * NH]) | ((unsigned)f2bf(bpg[1 * NH]) << 16);
                vg.y = f2bf(bpg[2 * NH]) | ((unsigned)f2bf(bpg[3 * NH]) << 16);
                vg.z = f2bf(bpg[4 * NH]) | ((unsigned)f2bf(bpg[5 * NH]) << 16);
                vg.w = f2bf(bpg[6 * NH]) | ((unsigned)f2bf(bpg[7 * NH]) << 16);
            }
            int sidx = sr * BK + ((ck ^ (sr & 7)) * 8);
            *(uint4*)&lB1[sidx] = v1;
            *(uint4*)&lBg[sidx] = vg;
        }
        __syncthreads();

#pragma unroll
        for (int kk = 0; kk < 2; ++kk) {
            bf16x8 af[4], bfrag[4];
#pragma unroll
            for (int m = 0; m < 4; ++m) {
                int r = wr * 64 + m * 16 + (lane & 15);
                int ch = kk * 4 + (lane >> 4);
                af[m] = *(const bf16x8*)&lA[r * BK + ((ch ^ (r & 7)) * 8)];
            }
#pragma unroll
            for (int n = 0; n < 4; ++n) {
                int c = wc * 64 + n * 16 + (lane & 15);
                int ch = kk * 4 + (lane >> 4);
                bfrag[n] = *(const bf16x8*)&lB1[c * BK + ((ch ^ (c & 7)) * 8)];
            }
#pragma unroll
            for (int m = 0; m < 4; ++m)
#pragma unroll
                for (int n = 0; n < 4; ++n)
                    acc1[m][n] = __builtin_amdgcn_mfma_f32_16x16x32_bf16(af[m], bfrag[n], acc1[m][n], 0, 0, 0);
#pragma unroll
            for (int n = 0; n < 4; ++n) {
                int c = wc * 64 + n * 16 + (lane & 15);
                int ch = kk * 4 + (lane >> 4);
                bfrag[n] = *(const bf16x8*)&lBg[c * BK + ((ch ^ (c & 7)) * 8)];
            }
#pragma unroll
            for (int m = 0; m < 4; ++m)
#pragma unroll
                for (int n = 0; n < 4; ++n)
                    accg[m][n] = __builtin_amdgcn_mfma_f32_16x16x32_bf16(af[m], bfrag[n], accg[m][n], 0, 0, 0);
        }
        __syncthreads();
    }

    // ---- epilogue: gate, fold routing weight, store bf16 h ----
#pragma unroll
    for (int m = 0; m < 4; ++m) {
#pragma unroll
        for (int rr = 0; rr < 4; ++rr) {
            int row = wr * 64 + m * 16 + (lane >> 4) * 4 + rr;
            int grow = row0 + row;
            float wt = pw[grow];
            size_t hb = (size_t)(grow - rowbase) * NH + col0;
#pragma unroll
            for (int n = 0; n < 4; ++n) {
                int col = wc * 64 + n * 16 + (lane & 15);
                float x = acc1[m][n][rr];
                float g = accg[m][n][rr];
                float hv = x * (1.f / (1.f + __expf(-g))) * wt;
                hbuf[hb + col] = f2bf(hv);
            }
        }
    }
}

// ---------------- GEMM2: out[token] += h @ W2  (k over full H) ----------------
template<bool PRE>
__global__ __launch_bounds__(256, 2) void gemm2_kernel(
    const unsigned short* __restrict__ hbuf, const float* __restrict__ W2,
    const unsigned short* __restrict__ W2t,
    const int* __restrict__ offsets, const int* __restrict__ ptok,
    float* __restrict__ out, int tile0)
{
    __shared__ unsigned short lA[BM * BK];
    __shared__ unsigned short lB[BN * BK];

    const int tid = threadIdx.x;
    const int lane = tid & 63;
    const int wid = tid >> 6;
    const int wr = wid >> 1, wc = wid & 1;
    const int row0 = (tile0 + blockIdx.x) * BM;
    const int rowbase = tile0 * BM;
    const int col0 = blockIdx.y * BN;      // D column

    int e = 0;
#pragma unroll
    for (int i = 1; i < NE; ++i) e += (row0 >= offsets[i]) ? 1 : 0;

    const int sr = tid >> 1;
    const int sck = (tid & 1) * 4;
    const int gcolB = col0 + sr;
    const size_t wbase = (size_t)e * NH * ND;

    f32x4 acc[4][4];
#pragma unroll
    for (int m = 0; m < 4; ++m)
#pragma unroll
        for (int n = 0; n < 4; ++n) acc[m][n] = (f32x4){0.f, 0.f, 0.f, 0.f};

    for (int k0 = 0; k0 < NH; k0 += BK) {
        // ---- stage A (h already bf16) ----
#pragma unroll
        for (int i = 0; i < 4; ++i) {
            int ck = sck + i;
            uint4 v = *(const uint4*)(hbuf + (size_t)(row0 - rowbase + sr) * NH + k0 + ck * 8);
            *(uint4*)&lA[sr * BK + ((ck ^ (sr & 7)) * 8)] = v;
        }
        // ---- stage B (W2) ----
#pragma unroll
        for (int i = 0; i < 4; ++i) {
            int ck = sck + i;
            uint4 v;
            if (PRE) {
                v = *(const uint4*)(W2t + wbase + (size_t)gcolB * NH + k0 + ck * 8);
            } else {
                const float* bp = W2 + wbase + (size_t)(k0 + ck * 8) * ND + gcolB;
                v.x = f2bf(bp[0 * ND]) | ((unsigned)f2bf(bp[1 * ND]) << 16);
                v.y = f2bf(bp[2 * ND]) | ((unsigned)f2bf(bp[3 * ND]) << 16);
                v.z = f2bf(bp[4 * ND]) | ((unsigned)f2bf(bp[5 * ND]) << 16);
                v.w = f2bf(bp[6 * ND]) | ((unsigned)f2bf(bp[7 * ND]) << 16);
            }
            *(uint4*)&lB[sr * BK + ((ck ^ (sr & 7)) * 8)] = v;
        }
        __syncthreads();

#pragma unroll
        for (int kk = 0; kk < 2; ++kk) {
            bf16x8 af[4], bfrag[4];
#pragma unroll
            for (int m = 0; m < 4; ++m) {
                int r = wr * 64 + m * 16 + (lane & 15);
                int ch = kk * 4 + (lane >> 4);
                af[m] = *(const bf16x8*)&lA[r * BK + ((ch ^ (r & 7)) * 8)];
            }
#pragma unroll
            for (int n = 0; n < 4; ++n) {
                int c = wc * 64 + n * 16 + (lane & 15);
                int ch = kk * 4 + (lane >> 4);
                bfrag[n] = *(const bf16x8*)&lB[c * BK + ((ch ^ (c & 7)) * 8)];
            }
#pragma unroll
            for (int m = 0; m < 4; ++m)
#pragma unroll
                for (int n = 0; n < 4; ++n)
                    acc[m][n] = __builtin_amdgcn_mfma_f32_16x16x32_bf16(af[m], bfrag[n], acc[m][n], 0, 0, 0);
        }
        __syncthreads();
    }

    // ---- epilogue: scatter-accumulate into out ----
#pragma unroll
    for (int m = 0; m < 4; ++m) {
#pragma unroll
        for (int rr = 0; rr < 4; ++rr) {
            int row = wr * 64 + m * 16 + (lane >> 4) * 4 + rr;
            int grow = row0 + row;
            int tok = ptok[grow];
            if (tok < 0) continue;
            float* op = out + (size_t)tok * ND + col0;
#pragma unroll
            for (int n = 0; n < 4; ++n) {
                int col = wc * 64 + n * 16 + (lane & 15);
                atomicAdd(op + col, acc[m][n][rr]);
            }
        }
    }
}

// ---------------- host ----------------
extern "C" void kernel_launch(void* const* d_in, const int* in_sizes, int n_in,
                              void* d_out, int out_size, void* d_ws, size_t ws_size,
                              hipStream_t stream) {
    const float* hidden = (const float*)d_in[0];
    const float* scores = (const float*)d_in[1];
    const float* W1 = (const float*)d_in[2];
    const float* Wg = (const float*)d_in[3];
    const float* W2 = (const float*)d_in[4];
    float* out = (float*)d_out;

    char* wsb = (char*)d_ws;
    int* counts = (int*)(wsb + 0);
    int* cursors = (int*)(wsb + 64);
    int* offsets = (int*)(wsb + 128);
    int* te = (int*)(wsb + 256);
    float* tw = (float*)(wsb + 256 + (size_t)NTOK * 2 * 4);
    int* ptok = (int*)(wsb + 256 + (size_t)NTOK * 2 * 8);
    float* pw = (float*)(wsb + 256 + (size_t)NTOK * 2 * 8 + (size_t)PADN * 4);
    size_t fixed = 256 + (size_t)NTOK * 2 * 8 + (size_t)PADN * 8;
    fixed = (fixed + 255) & ~(size_t)255;

    const size_t hidbf_b = (size_t)NTOK * ND * 2;            // 48 MB
    const size_t wt_b    = (size_t)NE * ND * NH * 2;         // 18.9 MB each
    const size_t wtot_b  = hidbf_b + 3 * wt_b;               // ~105 MB

    unsigned short* hidbf = (unsigned short*)(wsb + fixed);
    unsigned short* W1t = (unsigned short*)(wsb + fixed + hidbf_b);
    unsigned short* Wgt = (unsigned short*)(wsb + fixed + hidbf_b + wt_b);
    unsigned short* W2t = (unsigned short*)(wsb + fixed + hidbf_b + 2 * wt_b);

    // pick row-group size (tiles per group) and whether pre-conversion fits
    const int gcand[12] = {1, 2, 3, 4, 6, 8, 13, 26, 52, 104, 260, 520};
    bool pre = false;
    int tiles_pg = 1;
    unsigned short* hbuf = nullptr;
    for (int i = 0; i < 12; ++i) {
        int tpg = (ROWTILES + gcand[i] - 1) / gcand[i];
        size_t hb = (size_t)tpg * BM * NH * 2;
        if (fixed + wtot_b + hb <= ws_size) { pre = true; tiles_pg = tpg; break; }
    }
    if (pre) {
        hbuf = (unsigned short*)(wsb + fixed + wtot_b);
    } else {
        for (int i = 0; i < 12; ++i) {
            int tpg = (ROWTILES + gcand[i] - 1) / gcand[i];
            size_t hb = (size_t)tpg * BM * NH * 2;
            if (fixed + hb <= ws_size) { tiles_pg = tpg; break; }
            tiles_pg = 1;
        }
        hbuf = (unsigned short*)(wsb + fixed);
    }

    hipMemsetAsync(counts, 0, 256, stream);
    hipMemsetAsync(ptok, 0xFF, (size_t)PADN * 4, stream);
    hipMemsetAsync(pw, 0, (size_t)PADN * 4, stream);
    hipMemsetAsync(out, 0, (size_t)out_size * 4, stream);

    router_kernel<<<NTOK / 256, 256, 0, stream>>>(scores, counts, te, tw);
    scan_kernel<<<1, 64, 0, stream>>>(counts, offsets, cursors);
    fill_kernel<<<NTOK / 256, 256, 0, stream>>>(te, tw, cursors, ptok, pw);

    if (pre) {
        cvt_kernel<<<(NTOK * ND / 8 + 255) / 256, 256, 0, stream>>>(hidden, hidbf, NTOK * ND / 8);
        dim3 tg1(NH / 32, ND / 32, NE);   // W1/Wg: [D][H] -> [H][D]
        tcvt_kernel<<<tg1, 256, 0, stream>>>(W1, W1t, ND, NH);
        tcvt_kernel<<<tg1, 256, 0, stream>>>(Wg, Wgt, ND, NH);
        dim3 tg2(ND / 32, NH / 32, NE);   // W2: [H][D] -> [D][H]
        tcvt_kernel<<<tg2, 256, 0, stream>>>(W2, W2t, NH, ND);
    }

    for (int t0 = 0; t0 < ROWTILES; t0 += tiles_pg) {
        int nt = ROWTILES - t0 < tiles_pg ? ROWTILES - t0 : tiles_pg;
        dim3 g1(nt, NH / BN);
        dim3 g2(nt, ND / BN);
        if (pre) {
            gemm1_kernel<true><<<g1, 256, 0, stream>>>(hidden, hidbf, W1, Wg, W1t, Wgt,
                                                       offsets, ptok, pw, hbuf, t0);
            gemm2_kernel<true><<<g2, 256, 0, stream>>>(hbuf, W2, W2t, offsets, ptok, out, t0);
        } else {
            gemm1_kernel<false><<<g1, 256, 0, stream>>>(hidden, hidbf, W1, Wg, W1t, Wgt,
                                                        offsets, ptok, pw, hbuf, t0);
            gemm2_kernel<false><<<g2, 256, 0, stream>>>(hbuf, W2, W2t, offsets, ptok, out, t0);
        }
    }
}

// Round 4
// 1431.080 us; speedup vs baseline: 1.0399x; 1.0399x over previous
//
#include <hip/hip_runtime.h>
#include <hip/hip_bf16.h>

#define NB 8
#define NL 4096
#define ND 768
#define NE 8
#define NK 2
#define NH 1536
#define NTOK (NB*NL)        // 32768
#define NPAIR (NTOK*NK)     // 65536
#define BM 128
#define BN 128
#define BK 64
#define ROWTILES 520        // ceil((NPAIR + NE*(BM-1))/BM)
#define PADN (ROWTILES*BM)  // 66560

typedef __attribute__((ext_vector_type(8))) short bf16x8;
typedef __attribute__((ext_vector_type(4))) float f32x4;

static __device__ __forceinline__ unsigned short f2bf(float f) {
    union { float f; unsigned int u; } v; v.f = f;
    unsigned int r = v.u + 0x7fffu + ((v.u >> 16) & 1u);
    return (unsigned short)(r >> 16);
}

// async global->LDS, 16B per lane; LDS dest is wave-uniform base + lane*16
static __device__ __forceinline__ void gload16(const unsigned short* g, unsigned short* l) {
    __builtin_amdgcn_global_load_lds(
        (const __attribute__((address_space(1))) void*)g,
        (__attribute__((address_space(3))) void*)l, 16, 0, 0);
}

// ---------------- routing ----------------
__global__ void router_kernel(const float* __restrict__ scores,
                              int* __restrict__ counts,
                              int* __restrict__ te, float* __restrict__ tw) {
    int t = blockIdx.x * 256 + threadIdx.x;
    if (t >= NTOK) return;
    float s[NE];
#pragma unroll
    for (int e = 0; e < NE; ++e) s[e] = scores[t * NE + e];
    int i0 = 0; float m0 = s[0];
#pragma unroll
    for (int e = 1; e < NE; ++e) if (s[e] > m0) { m0 = s[e]; i0 = e; }
    int i1 = -1; float m1 = -1e30f;
#pragma unroll
    for (int e = 0; e < NE; ++e) if (e != i0 && s[e] > m1) { m1 = s[e]; i1 = e; }
    float z = expf(m1 - m0);            // <= 1
    float inv = 1.f / (1.f + z);
    te[t * 2 + 0] = i0; te[t * 2 + 1] = i1;
    tw[t * 2 + 0] = inv; tw[t * 2 + 1] = z * inv;
    atomicAdd(&counts[i0], 1);
    atomicAdd(&counts[i1], 1);
}

__global__ void scan_kernel(const int* __restrict__ counts,
                            int* __restrict__ offsets, int* __restrict__ cursors) {
    if (threadIdx.x == 0) {
        int off = 0;
        for (int e = 0; e < NE; ++e) {
            offsets[e] = off;
            cursors[e] = off;
            off += ((counts[e] + BM - 1) / BM) * BM;   // 128-aligned segments
        }
        offsets[NE] = off;
    }
}

__global__ void fill_kernel(const int* __restrict__ te, const float* __restrict__ tw,
                            int* __restrict__ cursors,
                            int* __restrict__ ptok, float* __restrict__ pw) {
    int t = blockIdx.x * 256 + threadIdx.x;
    if (t >= NTOK) return;
#pragma unroll
    for (int k = 0; k < NK; ++k) {
        int e = te[t * 2 + k];
        int pos = atomicAdd(&cursors[e], 1);
        ptok[pos] = t;
        pw[pos] = tw[t * 2 + k];
    }
}

// ---------------- operand pre-conversion ----------------
__global__ void cvt_kernel(const float* __restrict__ src, unsigned short* __restrict__ dst, int n8) {
    int i = blockIdx.x * 256 + threadIdx.x;
    if (i >= n8) return;
    const float4* p = (const float4*)(src + (size_t)i * 8);
    float4 a = p[0], b = p[1];
    uint4 v;
    v.x = f2bf(a.x) | ((unsigned)f2bf(a.y) << 16);
    v.y = f2bf(a.z) | ((unsigned)f2bf(a.w) << 16);
    v.z = f2bf(b.x) | ((unsigned)f2bf(b.y) << 16);
    v.w = f2bf(b.z) | ((unsigned)f2bf(b.w) << 16);
    *(uint4*)(dst + (size_t)i * 8) = v;
}

// per-expert transpose+convert: src [E][R][C] fp32 -> dst [E][C][R] bf16
__global__ void tcvt_kernel(const float* __restrict__ src, unsigned short* __restrict__ dst,
                            int R, int C) {
    __shared__ float t[32][33];
    int e = blockIdx.z;
    const float* s = src + (size_t)e * R * C;
    unsigned short* d = dst + (size_t)e * R * C;
    int c0 = blockIdx.x * 32, r0 = blockIdx.y * 32;
    int tx = threadIdx.x & 31, ty4 = (threadIdx.x >> 5) * 4;
#pragma unroll
    for (int i = 0; i < 4; ++i)
        t[ty4 + i][tx] = s[(size_t)(r0 + ty4 + i) * C + c0 + tx];
    __syncthreads();
#pragma unroll
    for (int i = 0; i < 4; ++i)
        d[(size_t)(c0 + ty4 + i) * R + r0 + tx] = f2bf(t[tx][ty4 + i]);
}

// ---------------- GEMM1: h = (X@W1) * sigmoid(X@Wg) * w  (bf16 out, full H) ----------------
template<bool PRE>
__global__ __launch_bounds__(256, 2) void gemm1_kernel(
    const float* __restrict__ hidden, const unsigned short* __restrict__ hidbf,
    const float* __restrict__ W1, const float* __restrict__ Wg,
    const unsigned short* __restrict__ W1t, const unsigned short* __restrict__ Wgt,
    const unsigned short* __restrict__ zbuf,
    const int* __restrict__ offsets, const int* __restrict__ ptok,
    const float* __restrict__ pw, unsigned short* __restrict__ hbuf, int tile0)
{
    __shared__ unsigned short lA[BM * BK];
    __shared__ unsigned short lB1[BN * BK];
    __shared__ unsigned short lBg[BN * BK];

    const int tid = threadIdx.x;
    const int lane = tid & 63;
    const int wid = tid >> 6;
    const int wr = wid >> 1, wc = wid & 1;
    const int row0 = (tile0 + blockIdx.x) * BM;   // global pair-row base
    const int rowbase = tile0 * BM;               // hbuf local base
    const int col0 = blockIdx.y * BN;             // H column base

    int e = 0;
#pragma unroll
    for (int i = 1; i < NE; ++i) e += (row0 >= offsets[i]) ? 1 : 0;
    const size_t wbase = (size_t)e * ND * NH;

    f32x4 acc1[4][4], accg[4][4];
#pragma unroll
    for (int m = 0; m < 4; ++m)
#pragma unroll
        for (int n = 0; n < 4; ++n) {
            acc1[m][n] = (f32x4){0.f, 0.f, 0.f, 0.f};
            accg[m][n] = (f32x4){0.f, 0.f, 0.f, 0.f};
        }

    if (PRE) {
        // pre-swizzled-source async staging (rule #21: linear LDS dest, permuted src)
        const int lr = lane >> 3;          // row within 8-row group
        const int csw = (lane & 7) ^ lr;   // swizzled source 16B-chunk
        const unsigned short* gA[4];
        const unsigned short* gB1[4];
        const unsigned short* gBg[4];
#pragma unroll
        for (int i = 0; i < 4; ++i) {
            int r = wid * 32 + i * 8 + lr;
            int tok = ptok[row0 + r];
            gA[i] = (tok >= 0 ? hidbf + (size_t)tok * ND : zbuf) + csw * 8;
            int c = col0 + r;
            gB1[i] = W1t + wbase + (size_t)c * ND + csw * 8;
            gBg[i] = Wgt + wbase + (size_t)c * ND + csw * 8;
        }
        for (int k0 = 0; k0 < ND; k0 += BK) {
#pragma unroll
            for (int i = 0; i < 4; ++i) {
                gload16(gA[i] + k0, &lA[(wid * 32 + i * 8) * BK]);
                gload16(gB1[i] + k0, &lB1[(wid * 32 + i * 8) * BK]);
                gload16(gBg[i] + k0, &lBg[(wid * 32 + i * 8) * BK]);
            }
            __syncthreads();
#pragma unroll
            for (int kk = 0; kk < 2; ++kk) {
                bf16x8 af[4], bfrag[4];
#pragma unroll
                for (int m = 0; m < 4; ++m) {
                    int r = wr * 64 + m * 16 + (lane & 15);
                    int ch = kk * 4 + (lane >> 4);
                    af[m] = *(const bf16x8*)&lA[r * BK + ((ch ^ (r & 7)) * 8)];
                }
#pragma unroll
                for (int n = 0; n < 4; ++n) {
                    int c = wc * 64 + n * 16 + (lane & 15);
                    int ch = kk * 4 + (lane >> 4);
                    bfrag[n] = *(const bf16x8*)&lB1[c * BK + ((ch ^ (c & 7)) * 8)];
                }
#pragma unroll
                for (int m = 0; m < 4; ++m)
#pragma unroll
                    for (int n = 0; n < 4; ++n)
                        acc1[m][n] = __builtin_amdgcn_mfma_f32_16x16x32_bf16(af[m], bfrag[n], acc1[m][n], 0, 0, 0);
#pragma unroll
                for (int n = 0; n < 4; ++n) {
                    int c = wc * 64 + n * 16 + (lane & 15);
                    int ch = kk * 4 + (lane >> 4);
                    bfrag[n] = *(const bf16x8*)&lBg[c * BK + ((ch ^ (c & 7)) * 8)];
                }
#pragma unroll
                for (int m = 0; m < 4; ++m)
#pragma unroll
                    for (int n = 0; n < 4; ++n)
                        accg[m][n] = __builtin_amdgcn_mfma_f32_16x16x32_bf16(af[m], bfrag[n], accg[m][n], 0, 0, 0);
            }
            __syncthreads();
        }
    } else {
        // fallback: in-loop fp32->bf16 reg-staging
        const int sr = tid >> 1;
        const int sck = (tid & 1) * 4;
        const int stok = ptok[row0 + sr];
        const int gcolB = col0 + sr;
        for (int k0 = 0; k0 < ND; k0 += BK) {
#pragma unroll
            for (int i = 0; i < 4; ++i) {
                int ck = sck + i;
                uint4 v;
                if (stok >= 0) {
                    const float4* p = (const float4*)(hidden + (size_t)stok * ND + k0 + ck * 8);
                    float4 f0 = p[0], f1 = p[1];
                    v.x = f2bf(f0.x) | ((unsigned)f2bf(f0.y) << 16);
                    v.y = f2bf(f0.z) | ((unsigned)f2bf(f0.w) << 16);
                    v.z = f2bf(f1.x) | ((unsigned)f2bf(f1.y) << 16);
                    v.w = f2bf(f1.z) | ((unsigned)f2bf(f1.w) << 16);
                } else v = make_uint4(0u, 0u, 0u, 0u);
                *(uint4*)&lA[sr * BK + ((ck ^ (sr & 7)) * 8)] = v;
            }
#pragma unroll
            for (int i = 0; i < 4; ++i) {
                int ck = sck + i;
                const float* bp1 = W1 + wbase + (size_t)(k0 + ck * 8) * NH + gcolB;
                const float* bpg = Wg + wbase + (size_t)(k0 + ck * 8) * NH + gcolB;
                uint4 v1, vg;
                v1.x = f2bf(bp1[0 * NH]) | ((unsigned)f2bf(bp1[1 * NH]) << 16);
                v1.y = f2bf(bp1[2 * NH]) | ((unsigned)f2bf(bp1[3 * NH]) << 16);
                v1.z = f2bf(bp1[4 * NH]) | ((unsigned)f2bf(bp1[5 * NH]) << 16);
                v1.w = f2bf(bp1[6 * NH]) | ((unsigned)f2bf(bp1[7 * NH]) << 16);
                vg.x = f2bf(bpg[0 * NH]) | ((unsigned)f2bf(bpg[1 * NH]) << 16);
                vg.y = f2bf(bpg[2 * NH]) | ((unsigned)f2bf(bpg[3 * NH]) << 16);
                vg.z = f2bf(bpg[4 * NH]) | ((unsigned)f2bf(bpg[5 * NH]) << 16);
                vg.w = f2bf(bpg[6 * NH]) | ((unsigned)f2bf(bpg[7 * NH]) << 16);
                int sidx = sr * BK + ((ck ^ (sr & 7)) * 8);
                *(uint4*)&lB1[sidx] = v1;
                *(uint4*)&lBg[sidx] = vg;
            }
            __syncthreads();
#pragma unroll
            for (int kk = 0; kk < 2; ++kk) {
                bf16x8 af[4], bfrag[4];
#pragma unroll
                for (int m = 0; m < 4; ++m) {
                    int r = wr * 64 + m * 16 + (lane & 15);
                    int ch = kk * 4 + (lane >> 4);
                    af[m] = *(const bf16x8*)&lA[r * BK + ((ch ^ (r & 7)) * 8)];
                }
#pragma unroll
                for (int n = 0; n < 4; ++n) {
                    int c = wc * 64 + n * 16 + (lane & 15);
                    int ch = kk * 4 + (lane >> 4);
                    bfrag[n] = *(const bf16x8*)&lB1[c * BK + ((ch ^ (c & 7)) * 8)];
                }
#pragma unroll
                for (int m = 0; m < 4; ++m)
#pragma unroll
                    for (int n = 0; n < 4; ++n)
                        acc1[m][n] = __builtin_amdgcn_mfma_f32_16x16x32_bf16(af[m], bfrag[n], acc1[m][n], 0, 0, 0);
#pragma unroll
                for (int n = 0; n < 4; ++n) {
                    int c = wc * 64 + n * 16 + (lane & 15);
                    int ch = kk * 4 + (lane >> 4);
                    bfrag[n] = *(const bf16x8*)&lBg[c * BK + ((ch ^ (c & 7)) * 8)];
                }
#pragma unroll
                for (int m = 0; m < 4; ++m)
#pragma unroll
                    for (int n = 0; n < 4; ++n)
                        accg[m][n] = __builtin_amdgcn_mfma_f32_16x16x32_bf16(af[m], bfrag[n], accg[m][n], 0, 0, 0);
            }
            __syncthreads();
        }
    }

    // ---- epilogue: gate, fold routing weight, store bf16 h ----
#pragma unroll
    for (int m = 0; m < 4; ++m) {
#pragma unroll
        for (int rr = 0; rr < 4; ++rr) {
            int row = wr * 64 + m * 16 + (lane >> 4) * 4 + rr;
            int grow = row0 + row;
            float wt = pw[grow];
            size_t hb = (size_t)(grow - rowbase) * NH + col0;
#pragma unroll
            for (int n = 0; n < 4; ++n) {
                int col = wc * 64 + n * 16 + (lane & 15);
                float x = acc1[m][n][rr];
                float g = accg[m][n][rr];
                float hv = x * (1.f / (1.f + __expf(-g))) * wt;
                hbuf[hb + col] = f2bf(hv);
            }
        }
    }
}

// ---------------- GEMM2: out[token] += h @ W2  (k over full H) ----------------
template<bool PRE>
__global__ __launch_bounds__(256, 2) void gemm2_kernel(
    const unsigned short* __restrict__ hbuf, const float* __restrict__ W2,
    const unsigned short* __restrict__ W2t,
    const int* __restrict__ offsets, const int* __restrict__ ptok,
    float* __restrict__ out, int tile0)
{
    __shared__ unsigned short lA[BM * BK];
    __shared__ unsigned short lB[BN * BK];

    const int tid = threadIdx.x;
    const int lane = tid & 63;
    const int wid = tid >> 6;
    const int wr = wid >> 1, wc = wid & 1;
    const int row0 = (tile0 + blockIdx.x) * BM;
    const int rowbase = tile0 * BM;
    const int col0 = blockIdx.y * BN;      // D column

    int e = 0;
#pragma unroll
    for (int i = 1; i < NE; ++i) e += (row0 >= offsets[i]) ? 1 : 0;
    const size_t wbase = (size_t)e * NH * ND;

    f32x4 acc[4][4];
#pragma unroll
    for (int m = 0; m < 4; ++m)
#pragma unroll
        for (int n = 0; n < 4; ++n) acc[m][n] = (f32x4){0.f, 0.f, 0.f, 0.f};

    if (PRE) {
        const int lr = lane >> 3;
        const int csw = (lane & 7) ^ lr;
        const unsigned short* gA[4];
        const unsigned short* gB[4];
#pragma unroll
        for (int i = 0; i < 4; ++i) {
            int r = wid * 32 + i * 8 + lr;
            gA[i] = hbuf + (size_t)(row0 - rowbase + r) * NH + csw * 8;
            gB[i] = W2t + wbase + (size_t)(col0 + r) * NH + csw * 8;
        }
        for (int k0 = 0; k0 < NH; k0 += BK) {
#pragma unroll
            for (int i = 0; i < 4; ++i) {
                gload16(gA[i] + k0, &lA[(wid * 32 + i * 8) * BK]);
                gload16(gB[i] + k0, &lB[(wid * 32 + i * 8) * BK]);
            }
            __syncthreads();
#pragma unroll
            for (int kk = 0; kk < 2; ++kk) {
                bf16x8 af[4], bfrag[4];
#pragma unroll
                for (int m = 0; m < 4; ++m) {
                    int r = wr * 64 + m * 16 + (lane & 15);
                    int ch = kk * 4 + (lane >> 4);
                    af[m] = *(const bf16x8*)&lA[r * BK + ((ch ^ (r & 7)) * 8)];
                }
#pragma unroll
                for (int n = 0; n < 4; ++n) {
                    int c = wc * 64 + n * 16 + (lane & 15);
                    int ch = kk * 4 + (lane >> 4);
                    bfrag[n] = *(const bf16x8*)&lB[c * BK + ((ch ^ (c & 7)) * 8)];
                }
#pragma unroll
                for (int m = 0; m < 4; ++m)
#pragma unroll
                    for (int n = 0; n < 4; ++n)
                        acc[m][n] = __builtin_amdgcn_mfma_f32_16x16x32_bf16(af[m], bfrag[n], acc[m][n], 0, 0, 0);
            }
            __syncthreads();
        }
    } else {
        const int sr = tid >> 1;
        const int sck = (tid & 1) * 4;
        const int gcolB = col0 + sr;
        for (int k0 = 0; k0 < NH; k0 += BK) {
#pragma unroll
            for (int i = 0; i < 4; ++i) {
                int ck = sck + i;
                uint4 v = *(const uint4*)(hbuf + (size_t)(row0 - rowbase + sr) * NH + k0 + ck * 8);
                *(uint4*)&lA[sr * BK + ((ck ^ (sr & 7)) * 8)] = v;
            }
#pragma unroll
            for (int i = 0; i < 4; ++i) {
                int ck = sck + i;
                const float* bp = W2 + wbase + (size_t)(k0 + ck * 8) * ND + gcolB;
                uint4 v;
                v.x = f2bf(bp[0 * ND]) | ((unsigned)f2bf(bp[1 * ND]) << 16);
                v.y = f2bf(bp[2 * ND]) | ((unsigned)f2bf(bp[3 * ND]) << 16);
                v.z = f2bf(bp[4 * ND]) | ((unsigned)f2bf(bp[5 * ND]) << 16);
                v.w = f2bf(bp[6 * ND]) | ((unsigned)f2bf(bp[7 * ND]) << 16);
                *(uint4*)&lB[sr * BK + ((ck ^ (sr & 7)) * 8)] = v;
            }
            __syncthreads();
#pragma unroll
            for (int kk = 0; kk < 2; ++kk) {
                bf16x8 af[4], bfrag[4];
#pragma unroll
                for (int m = 0; m < 4; ++m) {
                    int r = wr * 64 + m * 16 + (lane & 15);
                    int ch = kk * 4 + (lane >> 4);
                    af[m] = *(const bf16x8*)&lA[r * BK + ((ch ^ (r & 7)) * 8)];
                }
#pragma unroll
                for (int n = 0; n < 4; ++n) {
                    int c = wc * 64 + n * 16 + (lane & 15);
                    int ch = kk * 4 + (lane >> 4);
                    bfrag[n] = *(const bf16x8*)&lB[c * BK + ((ch ^ (c & 7)) * 8)];
                }
#pragma unroll
                for (int m = 0; m < 4; ++m)
#pragma unroll
                    for (int n = 0; n < 4; ++n)
                        acc[m][n] = __builtin_amdgcn_mfma_f32_16x16x32_bf16(af[m], bfrag[n], acc[m][n], 0, 0, 0);
            }
            __syncthreads();
        }
    }

    // ---- epilogue: scatter-accumulate into out ----
#pragma unroll
    for (int m = 0; m < 4; ++m) {
#pragma unroll
        for (int rr = 0; rr < 4; ++rr) {
            int row = wr * 64 + m * 16 + (lane >> 4) * 4 + rr;
            int grow = row0 + row;
            int tok = ptok[grow];
            if (tok < 0) continue;
            float* op = out + (size_t)tok * ND + col0;
#pragma unroll
            for (int n = 0; n < 4; ++n) {
                int col = wc * 64 + n * 16 + (lane & 15);
                atomicAdd(op + col, acc[m][n][rr]);
            }
        }
    }
}

// ---------------- host ----------------
extern "C" void kernel_launch(void* const* d_in, const int* in_sizes, int n_in,
                              void* d_out, int out_size, void* d_ws, size_t ws_size,
                              hipStream_t stream) {
    const float* hidden = (const float*)d_in[0];
    const float* scores = (const float*)d_in[1];
    const float* W1 = (const float*)d_in[2];
    const float* Wg = (const float*)d_in[3];
    const float* W2 = (const float*)d_in[4];
    float* out = (float*)d_out;

    char* wsb = (char*)d_ws;
    int* counts = (int*)(wsb + 0);
    int* cursors = (int*)(wsb + 64);
    int* offsets = (int*)(wsb + 128);
    unsigned short* zbuf = (unsigned short*)(wsb + 256);      // 1536B zero page
    int* te = (int*)(wsb + 2048);
    float* tw = (float*)(wsb + 2048 + (size_t)NTOK * 2 * 4);
    int* ptok = (int*)(wsb + 2048 + (size_t)NTOK * 2 * 8);
    float* pw = (float*)(wsb + 2048 + (size_t)NTOK * 2 * 8 + (size_t)PADN * 4);
    size_t fixed = 2048 + (size_t)NTOK * 2 * 8 + (size_t)PADN * 8;
    fixed = (fixed + 255) & ~(size_t)255;

    const size_t hidbf_b = (size_t)NTOK * ND * 2;            // 48 MB
    const size_t wt_b    = (size_t)NE * ND * NH * 2;         // 18.9 MB each
    const size_t wtot_b  = hidbf_b + 3 * wt_b;               // ~105 MB

    unsigned short* hidbf = (unsigned short*)(wsb + fixed);
    unsigned short* W1t = (unsigned short*)(wsb + fixed + hidbf_b);
    unsigned short* Wgt = (unsigned short*)(wsb + fixed + hidbf_b + wt_b);
    unsigned short* W2t = (unsigned short*)(wsb + fixed + hidbf_b + 2 * wt_b);

    const int gcand[12] = {1, 2, 3, 4, 6, 8, 13, 26, 52, 104, 260, 520};
    bool pre = false;
    int tiles_pg = 1;
    unsigned short* hbuf = nullptr;
    for (int i = 0; i < 12; ++i) {
        int tpg = (ROWTILES + gcand[i] - 1) / gcand[i];
        size_t hb = (size_t)tpg * BM * NH * 2;
        if (fixed + wtot_b + hb <= ws_size) { pre = true; tiles_pg = tpg; break; }
    }
    if (pre) {
        hbuf = (unsigned short*)(wsb + fixed + wtot_b);
    } else {
        for (int i = 0; i < 12; ++i) {
            int tpg = (ROWTILES + gcand[i] - 1) / gcand[i];
            size_t hb = (size_t)tpg * BM * NH * 2;
            if (fixed + hb <= ws_size) { tiles_pg = tpg; break; }
            tiles_pg = 1;
        }
        hbuf = (unsigned short*)(wsb + fixed);
    }

    hipMemsetAsync(counts, 0, 256, stream);
    hipMemsetAsync(zbuf, 0, 1536 + 256, stream);
    hipMemsetAsync(ptok, 0xFF, (size_t)PADN * 4, stream);
    hipMemsetAsync(pw, 0, (size_t)PADN * 4, stream);
    hipMemsetAsync(out, 0, (size_t)out_size * 4, stream);

    router_kernel<<<NTOK / 256, 256, 0, stream>>>(scores, counts, te, tw);
    scan_kernel<<<1, 64, 0, stream>>>(counts, offsets, cursors);
    fill_kernel<<<NTOK / 256, 256, 0, stream>>>(te, tw, cursors, ptok, pw);

    if (pre) {
        cvt_kernel<<<(NTOK * ND / 8 + 255) / 256, 256, 0, stream>>>(hidden, hidbf, NTOK * ND / 8);
        dim3 tg1(NH / 32, ND / 32, NE);   // W1/Wg: [D][H] -> [H][D]
        tcvt_kernel<<<tg1, 256, 0, stream>>>(W1, W1t, ND, NH);
        tcvt_kernel<<<tg1, 256, 0, stream>>>(Wg, Wgt, ND, NH);
        dim3 tg2(ND / 32, NH / 32, NE);   // W2: [H][D] -> [D][H]
        tcvt_kernel<<<tg2, 256, 0, stream>>>(W2, W2t, NH, ND);
    }

    for (int t0 = 0; t0 < ROWTILES; t0 += tiles_pg) {
        int nt = ROWTILES - t0 < tiles_pg ? ROWTILES - t0 : tiles_pg;
        dim3 g1(nt, NH / BN);
        dim3 g2(nt, ND / BN);
        if (pre) {
            gemm1_kernel<true><<<g1, 256, 0, stream>>>(hidden, hidbf, W1, Wg, W1t, Wgt, zbuf,
                                                       offsets, ptok, pw, hbuf, t0);
            gemm2_kernel<true><<<g2, 256, 0, stream>>>(hbuf, W2, W2t, offsets, ptok, out, t0);
        } else {
            gemm1_kernel<false><<<g1, 256, 0, stream>>>(hidden, hidbf, W1, Wg, W1t, Wgt, zbuf,
                                                        offsets, ptok, pw, hbuf, t0);
            gemm2_kernel<false><<<g2, 256, 0, stream>>>(hbuf, W2, W2t, offsets, ptok, out, t0);
        }
    }
}